// Round 12
// baseline (1216.993 us; speedup 1.0000x reference)
//
#include <hip/hip_runtime.h>
#include <hip/hip_fp16.h>

#define BB 4
#define N0 256
#define N1 256
#define NVOX 65536
#define NSUB 8
#define NLOR 32768
#define RAYLEN 256
#define CH 16
#define NPTS (NLOR * RAYLEN)
#define VOXQ 16384   // voxels per LDS quarter-plane tile (u32 f16x2 -> 64KB)
#define VOXT 32768   // fallback path tile
#define CCH 32       // chunk count: 32 chunks x 8 groups = 256 blocks
#define NBLK 256
#define NTHR 1024

__device__ __forceinline__ float upk_w(unsigned p) {
    return __half2float(__ushort_as_half((unsigned short)(p >> 16)));
}
__device__ __forceinline__ unsigned pk2(float a, float b) {
    __half2 h = __floats2half2_rn(a, b);
    return *reinterpret_cast<unsigned*>(&h);
}

// ============================ persistent mega-kernel ============================
// 256 blocks x 1024 threads (1 block/CU guaranteed resident). All 4 MLEM
// iterations inside; phases separated by a monotonic grid barrier:
//   arrival  = device-scope RELEASE fetch_add  (writes back this XCD's L2)
//   wait     = relaxed spin until cnt >= NBLK*phase, then ACQUIRE load
//              (invalidates L1/L2 so cross-XCD data is re-fetched)
__global__ __launch_bounds__(1024, 4) void k_mega(
    const float* __restrict__ osem,    // (B,NVOX)
    const float* __restrict__ data,    // (B,NSUB,NLOR)
    const float* __restrict__ mult,
    const float* __restrict__ contam,
    const float* __restrict__ adj,     // (B,NSUB,NVOX)
    const float* __restrict__ norm,    // (B)
    const int*   __restrict__ ray_idx, // (NSUB,NLOR,RAYLEN)
    const float* __restrict__ pw,
    const float* __restrict__ w1, const float* __restrict__ b1,
    const float* __restrict__ w2, const float* __restrict__ b2,
    const float* __restrict__ nwp,
    float* __restrict__ xtA, float* __restrict__ xtB,
    unsigned* __restrict__ part,       // (CCH,2,NVOX) f16x2
    unsigned* __restrict__ packed,     // (NPTS)
    float* __restrict__ backv,         // (NVOX,4)
    float* __restrict__ ratio,         // (NLOR,4)
    int* __restrict__ bar,             // [cnt] (memset to 0 before launch)
    float* __restrict__ out)           // (B,NVOX)
{
    __shared__ unsigned lds[16384];    // 64KB, re-purposed per phase
    const int bid = blockIdx.x;
    const int tid = threadIdx.x;
    int barph = 0;

    auto gbar = [&]() {
        __syncthreads();
        if (tid == 0) {
            ++barph;
            __hip_atomic_fetch_add(&bar[0], 1, __ATOMIC_RELEASE,
                                   __HIP_MEMORY_SCOPE_AGENT);
            const int target = NBLK * barph;
            while (__hip_atomic_load(&bar[0], __ATOMIC_RELAXED,
                                     __HIP_MEMORY_SCOPE_AGENT) < target)
                __builtin_amdgcn_s_sleep(8);
            (void)__hip_atomic_load(&bar[0], __ATOMIC_ACQUIRE,
                                    __HIP_MEMORY_SCOPE_AGENT);
        }
        __syncthreads();
    };

    // ---- P0: transpose osem -> xtA (NVOX,4) ----
    {
        int t = bid * NTHR + tid;
        if (t < NVOX) {
            float4 o;
            o.x = osem[t];
            o.y = osem[NVOX + t];
            o.z = osem[2 * NVOX + t];
            o.w = osem[3 * NVOX + t];
            ((float4*)xtA)[t] = o;
        }
    }
    gbar();

    float* xin = xtA;
    float* xout = xtB;
    for (int it = 0; it < 4; ++it) {
        const int s = it * 2;  // subsets 0,2,4,6
        const int*   rs = ray_idx + (size_t)s * NPTS;
        const float* ps = pw + (size_t)s * NPTS;

        // ---- P1: fused forward + ratio + pack. 4096 waves x 8 LORs ----
        {
            const int wv = bid * 16 + (tid >> 6);
            const int lane = tid & 63;
            const int half = lane >> 5;
            const int sub = lane & 31;
            for (int k = 0; k < 4; ++k) {
                const int l = wv * 8 + k * 2 + half;
                const long e0 = (long)l * 64;
                const long ea = e0 + sub, eb = e0 + sub + 32;

                int4   ida = ((const int4*)rs)[ea];
                float4 wa  = ((const float4*)ps)[ea];
                int4   idb = ((const int4*)rs)[eb];
                float4 wb  = ((const float4*)ps)[eb];

                uint4 pka, pkb;
                pka.x = (unsigned)ida.x | ((unsigned)__half_as_ushort(__float2half_rn(wa.x)) << 16);
                pka.y = (unsigned)ida.y | ((unsigned)__half_as_ushort(__float2half_rn(wa.y)) << 16);
                pka.z = (unsigned)ida.z | ((unsigned)__half_as_ushort(__float2half_rn(wa.z)) << 16);
                pka.w = (unsigned)ida.w | ((unsigned)__half_as_ushort(__float2half_rn(wa.w)) << 16);
                pkb.x = (unsigned)idb.x | ((unsigned)__half_as_ushort(__float2half_rn(wb.x)) << 16);
                pkb.y = (unsigned)idb.y | ((unsigned)__half_as_ushort(__float2half_rn(wb.y)) << 16);
                pkb.z = (unsigned)idb.z | ((unsigned)__half_as_ushort(__float2half_rn(wb.z)) << 16);
                pkb.w = (unsigned)idb.w | ((unsigned)__half_as_ushort(__float2half_rn(wb.w)) << 16);
                ((uint4*)packed)[ea] = pka;
                ((uint4*)packed)[eb] = pkb;

                float ax = 0.f, ay = 0.f, az = 0.f, aw = 0.f;
                float4 xv;
                xv = ((const float4*)xin)[ida.x];
                ax += xv.x * wa.x; ay += xv.y * wa.x; az += xv.z * wa.x; aw += xv.w * wa.x;
                xv = ((const float4*)xin)[ida.y];
                ax += xv.x * wa.y; ay += xv.y * wa.y; az += xv.z * wa.y; aw += xv.w * wa.y;
                xv = ((const float4*)xin)[ida.z];
                ax += xv.x * wa.z; ay += xv.y * wa.z; az += xv.z * wa.z; aw += xv.w * wa.z;
                xv = ((const float4*)xin)[ida.w];
                ax += xv.x * wa.w; ay += xv.y * wa.w; az += xv.z * wa.w; aw += xv.w * wa.w;
                xv = ((const float4*)xin)[idb.x];
                ax += xv.x * wb.x; ay += xv.y * wb.x; az += xv.z * wb.x; aw += xv.w * wb.x;
                xv = ((const float4*)xin)[idb.y];
                ax += xv.x * wb.y; ay += xv.y * wb.y; az += xv.z * wb.y; aw += xv.w * wb.y;
                xv = ((const float4*)xin)[idb.z];
                ax += xv.x * wb.z; ay += xv.y * wb.z; az += xv.z * wb.z; aw += xv.w * wb.z;
                xv = ((const float4*)xin)[idb.w];
                ax += xv.x * wb.w; ay += xv.y * wb.w; az += xv.z * wb.w; aw += xv.w * wb.w;

#pragma unroll
                for (int off = 16; off >= 1; off >>= 1) {
                    ax += __shfl_xor(ax, off);
                    ay += __shfl_xor(ay, off);
                    az += __shfl_xor(az, off);
                    aw += __shfl_xor(aw, off);
                }
                if (sub == 0) {
                    float fwd[4] = {ax, ay, az, aw};
                    float rr[4];
#pragma unroll
                    for (int b = 0; b < 4; ++b) {
                        long o = (long)b * (NSUB * NLOR) + (long)s * NLOR + l;
                        float m = mult[o];
                        float ee = m * (norm[b] * fwd[b]) + contam[o];
                        rr[b] = m * (1.0f - data[o] / ee);
                    }
                    ((float4*)ratio)[l] = make_float4(rr[0], rr[1], rr[2], rr[3]);
                }
            }
        }
        gbar();

        // ---- P2: backprojection, ds_pk_add_f16 into LDS quarter-plane ----
        {
            const int c = bid >> 3;           // chunk 0..31
            const int g = bid & 7;            // group 0..7
            const int p = g & 1;              // batch pair
            const unsigned lo = (unsigned)(g >> 1) * VOXQ;

            for (int q = tid; q < VOXQ; q += NTHR) lds[q] = 0u;
            __syncthreads();

            const unsigned abase = (unsigned)(uintptr_t)(&lds[0]);
            const int n4 = (NPTS / CCH) >> 2;           // 65536
            const uint4* src = (const uint4*)packed + (size_t)c * n4;
            const float2* rat2 = (const float2*)ratio;
            const int e0 = c * n4;

#define PKADD(u, R)                                                              \
    {                                                                            \
        unsigned q_ = ((u) & 0xffffu) - lo;                                      \
        if (q_ < VOXQ) {                                                         \
            float w_ = upk_w(u);                                                 \
            unsigned d_ = pk2(w_ * (R).x, w_ * (R).y);                           \
            unsigned a_ = abase + (q_ << 2);                                     \
            asm volatile("ds_pk_add_f16 %0, %1" :: "v"(a_), "v"(d_) : "memory"); \
        }                                                                        \
    }
#define PROC(P, R) PKADD(P.x, R) PKADD(P.y, R) PKADD(P.z, R) PKADD(P.w, R)

            for (int base4 = 0; base4 < n4; base4 += 4096) {
                const int ea = base4 + tid;
                uint4 A = src[ea];
                uint4 B = src[ea + 1024];
                uint4 C2 = src[ea + 2048];
                uint4 D = src[ea + 3072];
                float2 ra = rat2[(((e0 + ea) >> 6) << 1) + p];
                float2 rb = rat2[(((e0 + ea + 1024) >> 6) << 1) + p];
                float2 rc = rat2[(((e0 + ea + 2048) >> 6) << 1) + p];
                float2 rd = rat2[(((e0 + ea + 3072) >> 6) << 1) + p];
                PROC(A, ra) PROC(B, rb) PROC(C2, rc) PROC(D, rd)
            }
#undef PROC
#undef PKADD
            asm volatile("s_waitcnt lgkmcnt(0)" ::: "memory");
            __syncthreads();

            unsigned* dst = part + ((size_t)c * 2 + p) * NVOX + lo;
            for (int q = tid; q < VOXQ; q += NTHR) dst[q] = lds[q];
        }
        gbar();

        // ---- P3: reduce part -> backv (NVOX,4) f32 ----
        {
            int t = bid * NTHR + tid;
            if (t < 2 * NVOX) {
                int pr = t >> 16;     // 0..1
                int v = t & 65535;
                float s0 = 0.f, s1 = 0.f;
#pragma unroll
                for (int cc = 0; cc < CCH; ++cc) {
                    unsigned u = part[((size_t)cc * 2 + pr) * NVOX + v];
                    s0 += __half2float(__ushort_as_half((unsigned short)(u & 0xffffu)));
                    s1 += __half2float(__ushort_as_half((unsigned short)(u >> 16)));
                }
                ((float2*)backv)[(size_t)v * 2 + pr] = make_float2(s0, s1);
            }
        }
        gbar();

        // ---- P4: CNN + combine. 4 sub-blocks of 256 thr, each an 8x32 tile ----
        {
            const int sb = tid >> 8, stid = tid & 255;
            const int T = bid * 4 + sb;                 // 0..1023 tiles
            const int b = T >> 8;
            const int rem = T & 255;
            const int i0 = (rem >> 3) * 8;              // 32 row-tiles
            const int j0 = (rem & 7) * 32;              // 8 col-tiles

            float* img = (float*)lds + sb * 432;        // 12*36
            float* hsm = (float*)lds + 1728 + sb * 2720;// 8*340
            float* wsh = (float*)lds + 1728 + 4 * 2720; // 144+144+16
            float* ws1 = wsh;
            float* ws2 = wsh + 144;
            float* bs1 = wsh + 288;
            if (tid < 144) { ws1[tid] = w1[tid]; ws2[tid] = w2[tid]; }
            if (tid < 16) bs1[tid] = b1[tid];

            for (int q = stid; q < 432; q += 256) {
                int ii = q / 36, jj = q % 36;
                int gi = i0 - 2 + ii, gj = j0 - 2 + jj;
                float v = 0.f;
                if (gi >= 0 && gi < N0 && gj >= 0 && gj < N1)
                    v = xin[(size_t)(gi * N1 + gj) * 4 + b];
                img[q] = v;
            }
            __syncthreads();

            const int HA = 10 * 34;                     // 340
            const int li = stid >> 5, lj = stid & 31;
            float o = b2[0];
#pragma unroll
            for (int pass = 0; pass < 2; ++pass) {
                for (int q = stid; q < 8 * HA; q += 256) {
                    int c8 = q / HA, r = q % HA;
                    int c = pass * 8 + c8;
                    int ii = r / 34, jj = r % 34;
                    int gi = i0 - 1 + ii, gj = j0 - 1 + jj;
                    float hv = 0.f;
                    if (gi >= 0 && gi < N0 && gj >= 0 && gj < N1) {  // conv2 zero-pads h
                        float a = bs1[c];
#pragma unroll
                        for (int di = 0; di < 3; ++di)
#pragma unroll
                            for (int dj = 0; dj < 3; ++dj)
                                a += img[(ii + di) * 36 + (jj + dj)] *
                                     ws1[c * 9 + di * 3 + dj];
                        hv = fmaxf(a, 0.f);
                    }
                    hsm[q] = hv;
                }
                __syncthreads();
#pragma unroll
                for (int c8 = 0; c8 < 8; ++c8)
#pragma unroll
                    for (int di = 0; di < 3; ++di)
#pragma unroll
                        for (int dj = 0; dj < 3; ++dj)
                            o += hsm[c8 * HA + (li + di) * 34 + (lj + dj)] *
                                 ws2[(pass * 8 + c8) * 9 + di * 3 + dj];
                if (pass == 0) __syncthreads();
            }

            const float nw = nwp[0];
            const int pr = b >> 1, hi = b & 1;
            const int v = (i0 + li) * N1 + (j0 + lj);
            float2 bp = ((const float2*)backv)[(size_t)v * 2 + pr];
            float bk = hi ? bp.y : bp.x;
            float xv = img[(li + 2) * 36 + (lj + 2)];
            float x_data = bk * xv / adj[(size_t)b * NSUB * NVOX + (size_t)s * NVOX + v];
            float xnew = fmaxf(osem[(size_t)b * NVOX + v] - x_data + nw * o, 0.f);
            xout[(size_t)v * 4 + b] = xnew;
            if (it == 3) out[(size_t)b * NVOX + v] = xnew;
        }
        gbar();

        float* tmp = xin; xin = xout; xout = tmp;
    }
}

// ---------------- raw fallback (R3 path, used if workspace is small) ----------------
__global__ __launch_bounds__(256) void k_transpose(const float* __restrict__ osem,
                                                   float* __restrict__ xt) {
    int v = blockIdx.x * blockDim.x + threadIdx.x;
    if (v >= NVOX) return;
    float4 o;
    o.x = osem[0 * NVOX + v];
    o.y = osem[1 * NVOX + v];
    o.z = osem[2 * NVOX + v];
    o.w = osem[3 * NVOX + v];
    ((float4*)xt)[v] = o;
}

__global__ __launch_bounds__(256) void k_fwd(
    const int* __restrict__ ridx, const float* __restrict__ pw,
    const float* __restrict__ xt, const float* __restrict__ data,
    const float* __restrict__ mult, const float* __restrict__ contam,
    const float* __restrict__ norm, float* __restrict__ ratio)
{
    const int wave = threadIdx.x >> 6;
    const int lane = threadIdx.x & 63;
    const int l = blockIdx.x * 4 + wave;
    const long base = (long)l * RAYLEN;
    float ax = 0.f, ay = 0.f, az = 0.f, aw = 0.f;
#pragma unroll
    for (int k = 0; k < 4; ++k) {
        int r = lane + (k << 6);
        float wt = pw[base + r];
        float4 xv = ((const float4*)xt)[ridx[base + r]];
        ax += xv.x * wt; ay += xv.y * wt; az += xv.z * wt; aw += xv.w * wt;
    }
#pragma unroll
    for (int off = 32; off >= 1; off >>= 1) {
        ax += __shfl_xor(ax, off); ay += __shfl_xor(ay, off);
        az += __shfl_xor(az, off); aw += __shfl_xor(aw, off);
    }
    if (lane == 0) {
        float fwd[4] = {ax, ay, az, aw};
        float rr[4];
#pragma unroll
        for (int b = 0; b < 4; ++b) {
            long o = (long)b * (NSUB * NLOR) + l;
            float m = mult[o];
            float e = m * (norm[b] * fwd[b]) + contam[o];
            rr[b] = m * (1.0f - data[o] / e);
        }
        ((float4*)ratio)[l] = make_float4(rr[0], rr[1], rr[2], rr[3]);
    }
}

__global__ __launch_bounds__(1024) void k_back(
    const int* __restrict__ ridx, const float* __restrict__ pw,
    const float* __restrict__ ratio, float* __restrict__ part, int PC)
{
    __shared__ float acc[VOXT];
    const int c = blockIdx.x;
    const int g = blockIdx.y;
    const int b = g & 3;
    const int lo = (g >> 2) * VOXT;
    for (int q = threadIdx.x; q < VOXT; q += 1024) acc[q] = 0.0f;
    __syncthreads();
    const int pbeg = c * PC;
    const int pend = min(pbeg + PC, NPTS);
#pragma unroll 2
    for (int pt = pbeg + (int)threadIdx.x * 4; pt < pend; pt += 1024 * 4) {
        int4   id = *(const int4*)(ridx + pt);
        float4 w  = *(const float4*)(pw + pt);
        float  r  = ratio[(pt >> 8) * 4 + b];
        unsigned r0 = (unsigned)(id.x - lo), r1 = (unsigned)(id.y - lo);
        unsigned r2 = (unsigned)(id.z - lo), r3 = (unsigned)(id.w - lo);
        if (r0 < VOXT) atomicAdd(&acc[r0], w.x * r);
        if (r1 < VOXT) atomicAdd(&acc[r1], w.y * r);
        if (r2 < VOXT) atomicAdd(&acc[r2], w.z * r);
        if (r3 < VOXT) atomicAdd(&acc[r3], w.w * r);
    }
    __syncthreads();
    float4* dst = (float4*)(part + ((size_t)c * 4 + b) * NVOX + lo);
    const float4* srcl = (const float4*)acc;
    for (int q = threadIdx.x; q < VOXT / 4; q += 1024) dst[q] = srcl[q];
}

__global__ __launch_bounds__(256) void k_conv1(
    const float* __restrict__ xt, const float* __restrict__ w1,
    const float* __restrict__ b1, float* __restrict__ h)
{
    int t = blockIdx.x * blockDim.x + threadIdx.x;
    int b = t >> 16;
    int v = t & 65535;
    int i = v >> 8, j = v & 255;
    float in[3][3];
#pragma unroll
    for (int di = 0; di < 3; ++di)
#pragma unroll
        for (int dj = 0; dj < 3; ++dj) {
            int ii = i + di - 1, jj = j + dj - 1;
            in[di][dj] = (ii >= 0 && ii < N0 && jj >= 0 && jj < N1)
                             ? xt[(size_t)((ii << 8) | jj) * 4 + b]
                             : 0.0f;
        }
    float* hp = h + (size_t)t * CH;
#pragma unroll
    for (int c = 0; c < CH; ++c) {
        float acc = b1[c];
#pragma unroll
        for (int di = 0; di < 3; ++di)
#pragma unroll
            for (int dj = 0; dj < 3; ++dj)
                acc += in[di][dj] * w1[c * 9 + di * 3 + dj];
        hp[c] = fmaxf(acc, 0.0f);
    }
}

__global__ __launch_bounds__(256) void k_combine(
    const float* __restrict__ h, const float* __restrict__ w2,
    const float* __restrict__ b2, const float* __restrict__ part,
    const float* __restrict__ xt_in, const float* __restrict__ osem,
    const float* __restrict__ adj, const float* __restrict__ nwp, int C,
    float* __restrict__ xt_out, float* __restrict__ out_planar)
{
    int t = blockIdx.x * blockDim.x + threadIdx.x;
    int b = t >> 16;
    int v = t & 65535;
    int i = v >> 8, j = v & 255;
    float o = b2[0];
#pragma unroll
    for (int di = 0; di < 3; ++di) {
        int ii = i + di - 1;
        if (ii < 0 || ii >= N0) continue;
#pragma unroll
        for (int dj = 0; dj < 3; ++dj) {
            int jj = j + dj - 1;
            if (jj < 0 || jj >= N1) continue;
            const float* hp = h + ((size_t)b * NVOX + ((ii << 8) | jj)) * CH;
#pragma unroll
            for (int c = 0; c < CH; ++c)
                o += hp[c] * w2[c * 9 + di * 3 + dj];
        }
    }
    float bk = 0.0f;
    for (int c = 0; c < C; ++c)
        bk += part[((size_t)c * 4 + b) * NVOX + v];
    float xv = xt_in[(size_t)v * 4 + b];
    float x_data = bk * xv / adj[(size_t)b * NSUB * NVOX + v];
    float xnew = osem[t] - x_data + nwp[0] * o;
    xnew = fmaxf(xnew, 0.0f);
    xt_out[(size_t)v * 4 + b] = xnew;
    if (out_planar) out_planar[t] = xnew;
}
// ------------------------------------------------------------------------------------

extern "C" void kernel_launch(void* const* d_in, const int* in_sizes, int n_in,
                              void* d_out, int out_size, void* d_ws, size_t ws_size,
                              hipStream_t stream) {
    const float* osem   = (const float*)d_in[0];
    const float* data   = (const float*)d_in[1];
    const float* mult   = (const float*)d_in[2];
    const float* contam = (const float*)d_in[3];
    const float* adj    = (const float*)d_in[4];
    const float* norm   = (const float*)d_in[5];
    const int*   ray_idx = (const int*)d_in[6];
    const float* pw     = (const float*)d_in[7];
    const float* w1     = (const float*)d_in[8];
    const float* b1     = (const float*)d_in[9];
    const float* w2     = (const float*)d_in[10];
    const float* b2     = (const float*)d_in[11];
    const float* nw     = (const float*)d_in[12];
    float* out = (float*)d_out;

    const size_t MB = 1024 * 1024;
    float* ws  = (float*)d_ws;

    bool use_mega = (ws_size >= 90 * MB);

    if (use_mega) {
        // layout: xtA(1M) xtB(1M) part(16.8M) packed(33.5M) backv(1M) ratio(0.5M) bar
        float*    xtA    = ws;
        float*    xtB    = xtA + (size_t)NVOX * 4;
        unsigned* part   = (unsigned*)(xtB + (size_t)NVOX * 4);
        unsigned* packed = part + (size_t)CCH * 2 * NVOX;
        float*    backv  = (float*)(packed + (size_t)NPTS);
        float*    ratio  = backv + (size_t)NVOX * 4;
        int*      bar    = (int*)(ratio + (size_t)NLOR * 4);

        hipMemsetAsync(bar, 0, 2 * sizeof(int), stream);
        k_mega<<<NBLK, NTHR, 0, stream>>>(
            osem, data, mult, contam, adj, norm, ray_idx, pw,
            w1, b1, w2, b2, nw,
            xtA, xtB, part, packed, backv, ratio, bar, out);
    } else {
        float* xtA = ws;
        float* xtB = ws + (size_t)NVOX * 4;
        const int subsets[4] = {0, 2, 4, 6};
        int C = (ws_size >= (18 + 32) * MB + NVOX) ? 32
              : (ws_size >= (18 + 16) * MB + NVOX) ? 16 : 8;
        const int PC = NPTS / C;
        float* part = ws + (size_t)NVOX * 8;
        float* h    = part + (size_t)C * NVOX * 4;
        float* ratio = h;

        k_transpose<<<NVOX / 256, 256, 0, stream>>>(osem, xtA);

        float* xin = xtA;
        float* xout = xtB;
        for (int it = 0; it < 4; ++it) {
            int s = subsets[it];
            const int*   rs = ray_idx + (size_t)s * NPTS;
            const float* ps = pw + (size_t)s * NPTS;
            k_fwd<<<NLOR / 4, 256, 0, stream>>>(
                rs, ps, xin,
                data + (size_t)s * NLOR, mult + (size_t)s * NLOR,
                contam + (size_t)s * NLOR, norm, ratio);
            k_back<<<dim3(C, 8), 1024, 0, stream>>>(rs, ps, ratio, part, PC);
            k_conv1<<<(BB * NVOX) / 256, 256, 0, stream>>>(xin, w1, b1, h);
            k_combine<<<(BB * NVOX) / 256, 256, 0, stream>>>(
                h, w2, b2, part, xin, osem,
                adj + (size_t)s * NVOX, nw, C,
                xout, (it == 3) ? out : nullptr);
            float* tmp = xin; xin = xout; xout = tmp;
        }
    }
}

// Round 13
// 661.096 us; speedup vs baseline: 1.8409x; 1.8409x over previous
//
#include <hip/hip_runtime.h>
#include <hip/hip_fp16.h>

#define BB 4
#define N0 256
#define N1 256
#define NVOX 65536
#define NSUB 8
#define NLOR 32768
#define RAYLEN 256
#define CH 16
#define NPTS (NLOR * RAYLEN)
#define VOXQ 16384   // voxels per LDS quarter-plane tile (u32 f16x2 -> 64KB)
#define VOXT 32768   // fallback path tile
#define CCH 32       // chunk count (pk path): 256 back blocks = 1/CU

// Transpose osem (B, NVOX) planar -> xt (NVOX, 4) so ray gathers are one float4.
__global__ __launch_bounds__(256) void k_transpose(const float* __restrict__ osem,
                                                   float* __restrict__ xt) {
    int v = blockIdx.x * blockDim.x + threadIdx.x;
    if (v >= NVOX) return;
    float4 o;
    o.x = osem[0 * NVOX + v];
    o.y = osem[1 * NVOX + v];
    o.z = osem[2 * NVOX + v];
    o.w = osem[3 * NVOX + v];
    ((float4*)xt)[v] = o;
}

__device__ __forceinline__ float upk_w(unsigned p) {
    return __half2float(__ushort_as_half((unsigned short)(p >> 16)));
}

__device__ __forceinline__ unsigned pk2(float a, float b) {
    __half2 h = __floats2half2_rn(a, b);
    return *reinterpret_cast<unsigned*>(&h);
}

// Fused forward projection + ratio + packing. One wave handles TWO LORs
// (32 lanes each); each thread owns 8 points -> 4 stream loads + 8 gathers
// in flight.
__global__ __launch_bounds__(256) void k_fwdpack(
    const int* __restrict__ ridx,     // ray_idx + s*NPTS
    const float* __restrict__ pw,     // proj_weights + s*NPTS
    const float* __restrict__ xt,     // (NVOX,4)
    const float* __restrict__ data,   // + index b*NSUB*NLOR + l
    const float* __restrict__ mult,
    const float* __restrict__ contam,
    const float* __restrict__ norm,   // (B)
    float* __restrict__ ratio,        // (NLOR,4)
    unsigned* __restrict__ packed)    // (NPTS) u16 idx | f16 w
{
    const int wave = threadIdx.x >> 6;
    const int lane = threadIdx.x & 63;
    const int half = lane >> 5;           // which LOR of the wave's pair
    const int sub  = lane & 31;
    const int l = blockIdx.x * 8 + wave * 2 + half;
    const long e0 = (long)l * 64;         // uint4-elems per LOR = 64

    const long ea = e0 + sub;
    const long eb = e0 + sub + 32;

    int4   ida = ((const int4*)ridx)[ea];
    float4 wa  = ((const float4*)pw)[ea];
    int4   idb = ((const int4*)ridx)[eb];
    float4 wb  = ((const float4*)pw)[eb];

    uint4 pka, pkb;
    pka.x = (unsigned)ida.x | ((unsigned)__half_as_ushort(__float2half_rn(wa.x)) << 16);
    pka.y = (unsigned)ida.y | ((unsigned)__half_as_ushort(__float2half_rn(wa.y)) << 16);
    pka.z = (unsigned)ida.z | ((unsigned)__half_as_ushort(__float2half_rn(wa.z)) << 16);
    pka.w = (unsigned)ida.w | ((unsigned)__half_as_ushort(__float2half_rn(wa.w)) << 16);
    pkb.x = (unsigned)idb.x | ((unsigned)__half_as_ushort(__float2half_rn(wb.x)) << 16);
    pkb.y = (unsigned)idb.y | ((unsigned)__half_as_ushort(__float2half_rn(wb.y)) << 16);
    pkb.z = (unsigned)idb.z | ((unsigned)__half_as_ushort(__float2half_rn(wb.z)) << 16);
    pkb.w = (unsigned)idb.w | ((unsigned)__half_as_ushort(__float2half_rn(wb.w)) << 16);
    ((uint4*)packed)[ea] = pka;
    ((uint4*)packed)[eb] = pkb;

    float ax = 0.f, ay = 0.f, az = 0.f, aw = 0.f;
    {
        float4 xv;
        xv = ((const float4*)xt)[ida.x];
        ax += xv.x * wa.x; ay += xv.y * wa.x; az += xv.z * wa.x; aw += xv.w * wa.x;
        xv = ((const float4*)xt)[ida.y];
        ax += xv.x * wa.y; ay += xv.y * wa.y; az += xv.z * wa.y; aw += xv.w * wa.y;
        xv = ((const float4*)xt)[ida.z];
        ax += xv.x * wa.z; ay += xv.y * wa.z; az += xv.z * wa.z; aw += xv.w * wa.z;
        xv = ((const float4*)xt)[ida.w];
        ax += xv.x * wa.w; ay += xv.y * wa.w; az += xv.z * wa.w; aw += xv.w * wa.w;
        xv = ((const float4*)xt)[idb.x];
        ax += xv.x * wb.x; ay += xv.y * wb.x; az += xv.z * wb.x; aw += xv.w * wb.x;
        xv = ((const float4*)xt)[idb.y];
        ax += xv.x * wb.y; ay += xv.y * wb.y; az += xv.z * wb.y; aw += xv.w * wb.y;
        xv = ((const float4*)xt)[idb.z];
        ax += xv.x * wb.z; ay += xv.y * wb.z; az += xv.z * wb.z; aw += xv.w * wb.z;
        xv = ((const float4*)xt)[idb.w];
        ax += xv.x * wb.w; ay += xv.y * wb.w; az += xv.z * wb.w; aw += xv.w * wb.w;
    }
    // butterfly reduce within each 32-lane half (lane^off keeps bit5)
#pragma unroll
    for (int off = 16; off >= 1; off >>= 1) {
        ax += __shfl_xor(ax, off);
        ay += __shfl_xor(ay, off);
        az += __shfl_xor(az, off);
        aw += __shfl_xor(aw, off);
    }
    if (sub == 0) {
        float fwd[4] = {ax, ay, az, aw};
        float rr[4];
#pragma unroll
        for (int b = 0; b < 4; ++b) {
            long o = (long)b * (NSUB * NLOR) + l;
            float m = mult[o];
            float ee = m * (norm[b] * fwd[b]) + contam[o];
            rr[b] = m * (1.0f - data[o] / ee);
        }
        ((float4*)ratio)[l] = make_float4(rr[0], rr[1], rr[2], rr[3]);
    }
}

// Backprojection with PACKED f16x2 LDS atomics (ds_pk_add_f16 via inline asm):
// block (chunk c, group g) owns batch-pair p=g&1 and voxel quarter g>>1.
__global__ __launch_bounds__(1024) void k_back_pk(
    const unsigned* __restrict__ packed,  // subset's packed stream
    const float* __restrict__ ratio,      // (NLOR,4) = (NLOR,2) float2 pairs
    unsigned* __restrict__ part,          // (CCH, 2, NVOX) f16x2 partials
    int PC)                               // points per chunk
{
    __shared__ unsigned acc[VOXQ];
    const int c = blockIdx.x;
    const int g = blockIdx.y;             // 0..7
    const int p = g & 1;                  // batch pair (batches 2p, 2p+1)
    const unsigned lo = (unsigned)(g >> 1) * VOXQ;

    for (int q = threadIdx.x; q < VOXQ; q += 1024) acc[q] = 0u;
    __syncthreads();

    const unsigned abase = (unsigned)(uintptr_t)(&acc[0]);

    const int n4 = PC >> 2;                         // uint4 elems in this chunk
    const uint4* src = (const uint4*)packed + (size_t)c * n4;
    const float2* rat2 = (const float2*)ratio;
    const int e0 = c * n4;

#define PKADD(u, R)                                                              \
    {                                                                            \
        unsigned q_ = ((u) & 0xffffu) - lo;                                      \
        if (q_ < VOXQ) {                                                         \
            float w_ = upk_w(u);                                                 \
            unsigned d_ = pk2(w_ * (R).x, w_ * (R).y);                           \
            unsigned a_ = abase + (q_ << 2);                                     \
            asm volatile("ds_pk_add_f16 %0, %1" :: "v"(a_), "v"(d_) : "memory"); \
        }                                                                        \
    }
#define PROC(P, R) PKADD(P.x, R) PKADD(P.y, R) PKADD(P.z, R) PKADD(P.w, R)

    for (int base4 = 0; base4 < n4; base4 += 4096) {
        const int ea = base4 + (int)threadIdx.x;
        uint4 A = src[ea];
        uint4 B = src[ea + 1024];
        uint4 C2 = src[ea + 2048];
        uint4 D = src[ea + 3072];
        float2 ra = rat2[(((e0 + ea) >> 6) << 1) + p];
        float2 rb = rat2[(((e0 + ea + 1024) >> 6) << 1) + p];
        float2 rc = rat2[(((e0 + ea + 2048) >> 6) << 1) + p];
        float2 rd = rat2[(((e0 + ea + 3072) >> 6) << 1) + p];
        PROC(A, ra) PROC(B, rb) PROC(C2, rc) PROC(D, rd)
    }
#undef PROC
#undef PKADD

    // drain our asm ds ops (compiler doesn't track them) before the barrier
    asm volatile("s_waitcnt lgkmcnt(0)" ::: "memory");
    __syncthreads();

    unsigned* dst = part + ((size_t)c * 2 + p) * NVOX + lo;
    for (int q = threadIdx.x; q < VOXQ; q += 1024) dst[q] = acc[q];
}

// High-occupancy streaming reduction: part (CCH,2,NVOX) f16x2 -> back (NVOX,4) f32.
// Thread handles 2 consecutive voxels via uint2 loads; full unroll for MLP.
__global__ __launch_bounds__(256) void k_reduce(
    const unsigned* __restrict__ part,
    float* __restrict__ back)
{
    const int t = blockIdx.x * 256 + threadIdx.x;
    const int v0 = t * 2;
    const int pr = blockIdx.y;
    float s0 = 0.f, s1 = 0.f, s2 = 0.f, s3 = 0.f;
#pragma unroll
    for (int cc = 0; cc < CCH; ++cc) {
        uint2 u = *(const uint2*)&part[((size_t)cc * 2 + pr) * NVOX + v0];
        s0 += __half2float(__ushort_as_half((unsigned short)(u.x & 0xffffu)));
        s1 += __half2float(__ushort_as_half((unsigned short)(u.x >> 16)));
        s2 += __half2float(__ushort_as_half((unsigned short)(u.y & 0xffffu)));
        s3 += __half2float(__ushort_as_half((unsigned short)(u.y >> 16)));
    }
    ((float2*)back)[(size_t)v0 * 2 + pr] = make_float2(s0, s1);
    ((float2*)back)[(size_t)(v0 + 1) * 2 + pr] = make_float2(s2, s3);
}

// Fused CNN (conv1+relu+conv2) + MLEM combine. 8x32 tile (1 px/thread),
// conv channel-split into 2 passes of 8 -> ~13KB LDS, 1024 blocks, 16 waves/CU.
// hsm OUTSIDE the image is ZERO (reference conv2 zero-pads h).
#define TI 8
#define TJ 32
__global__ __launch_bounds__(256) void k_net_combine(
    const float* __restrict__ xt_in,  // (NVOX,4)
    const float* __restrict__ w1,     // (16,1,3,3)
    const float* __restrict__ b1,     // (16)
    const float* __restrict__ w2,     // (1,16,3,3)
    const float* __restrict__ b2,     // (1)
    const float* __restrict__ back,   // (NVOX,4) f32
    const float* __restrict__ osem,   // (B,NVOX)
    const float* __restrict__ adj,    // adjoint_ones + s*..., index b*NSUB*NVOX+v
    const float* __restrict__ nwp,    // scalar
    float* __restrict__ xt_out,       // (NVOX,4)
    float* __restrict__ out_planar)   // (B,NVOX) or nullptr
{
    __shared__ float img[(TI + 4) * (TJ + 4)];        // 12*36 = 432
    __shared__ float hsm[8 * (TI + 2) * (TJ + 2)];    // 8*340 = 10.9KB
    __shared__ float ws1[144], ws2[144], bs1[16];

    const int i0 = blockIdx.x * TI;
    const int j0 = blockIdx.y * TJ;
    const int b  = blockIdx.z;
    const int tid = threadIdx.x;

    if (tid < 144) { ws1[tid] = w1[tid]; ws2[tid] = w2[tid]; }
    if (tid < 16) bs1[tid] = b1[tid];

    for (int q = tid; q < (TI + 4) * (TJ + 4); q += 256) {
        int ii = q / (TJ + 4), jj = q % (TJ + 4);
        int gi = i0 - 2 + ii, gj = j0 - 2 + jj;
        float v = 0.f;
        if (gi >= 0 && gi < N0 && gj >= 0 && gj < N1)
            v = xt_in[(size_t)(gi * N1 + gj) * 4 + b];
        img[q] = v;
    }
    __syncthreads();

    const int li = tid >> 5, lj = tid & 31;           // 8x32 = 256 = blockDim ✓
    const int HA = (TI + 2) * (TJ + 2);               // 340
    float o = b2[0];

#pragma unroll
    for (int pass = 0; pass < 2; ++pass) {
        for (int q = tid; q < 8 * HA; q += 256) {
            int c8 = q / HA, r = q % HA;
            int c = pass * 8 + c8;
            int ii = r / (TJ + 2), jj = r % (TJ + 2);
            int gi = i0 - 1 + ii, gj = j0 - 1 + jj;
            float hv = 0.f;
            if (gi >= 0 && gi < N0 && gj >= 0 && gj < N1) {  // conv2 zero-pads h
                float a = bs1[c];
#pragma unroll
                for (int di = 0; di < 3; ++di)
#pragma unroll
                    for (int dj = 0; dj < 3; ++dj)
                        a += img[(ii + di) * (TJ + 4) + (jj + dj)] *
                             ws1[c * 9 + di * 3 + dj];
                hv = fmaxf(a, 0.f);
            }
            hsm[q] = hv;
        }
        __syncthreads();
#pragma unroll
        for (int c8 = 0; c8 < 8; ++c8)
#pragma unroll
            for (int di = 0; di < 3; ++di)
#pragma unroll
                for (int dj = 0; dj < 3; ++dj)
                    o += hsm[c8 * HA + (li + di) * (TJ + 2) + (lj + dj)] *
                         ws2[(pass * 8 + c8) * 9 + di * 3 + dj];
        if (pass == 0) __syncthreads();
    }

    const float nw = nwp[0];
    const int pr = b >> 1, hi = b & 1;
    const int v = (i0 + li) * N1 + (j0 + lj);
    float2 bp = ((const float2*)back)[(size_t)v * 2 + pr];
    float bk = hi ? bp.y : bp.x;
    float xv = img[(li + 2) * (TJ + 4) + (lj + 2)];   // center pixel from LDS
    float x_data = bk * xv / adj[(size_t)b * NSUB * NVOX + v];
    float xnew = fmaxf(osem[(size_t)b * NVOX + v] - x_data + nw * o, 0.f);
    xt_out[(size_t)v * 4 + b] = xnew;
    if (out_planar) out_planar[(size_t)b * NVOX + v] = xnew;
}

// ---------------- raw fallback (R3 path, used if workspace is small) ----------------
__global__ __launch_bounds__(256) void k_fwd(
    const int* __restrict__ ridx, const float* __restrict__ pw,
    const float* __restrict__ xt, const float* __restrict__ data,
    const float* __restrict__ mult, const float* __restrict__ contam,
    const float* __restrict__ norm, float* __restrict__ ratio)
{
    const int wave = threadIdx.x >> 6;
    const int lane = threadIdx.x & 63;
    const int l = blockIdx.x * 4 + wave;
    const long base = (long)l * RAYLEN;
    float ax = 0.f, ay = 0.f, az = 0.f, aw = 0.f;
#pragma unroll
    for (int k = 0; k < 4; ++k) {
        int r = lane + (k << 6);
        float wt = pw[base + r];
        float4 xv = ((const float4*)xt)[ridx[base + r]];
        ax += xv.x * wt; ay += xv.y * wt; az += xv.z * wt; aw += xv.w * wt;
    }
#pragma unroll
    for (int off = 32; off >= 1; off >>= 1) {
        ax += __shfl_xor(ax, off); ay += __shfl_xor(ay, off);
        az += __shfl_xor(az, off); aw += __shfl_xor(aw, off);
    }
    if (lane == 0) {
        float fwd[4] = {ax, ay, az, aw};
        float rr[4];
#pragma unroll
        for (int b = 0; b < 4; ++b) {
            long o = (long)b * (NSUB * NLOR) + l;
            float m = mult[o];
            float e = m * (norm[b] * fwd[b]) + contam[o];
            rr[b] = m * (1.0f - data[o] / e);
        }
        ((float4*)ratio)[l] = make_float4(rr[0], rr[1], rr[2], rr[3]);
    }
}

__global__ __launch_bounds__(1024) void k_back(
    const int* __restrict__ ridx, const float* __restrict__ pw,
    const float* __restrict__ ratio, float* __restrict__ part, int PC)
{
    __shared__ float acc[VOXT];
    const int c = blockIdx.x;
    const int g = blockIdx.y;
    const int b = g & 3;
    const int lo = (g >> 2) * VOXT;
    for (int q = threadIdx.x; q < VOXT; q += 1024) acc[q] = 0.0f;
    __syncthreads();
    const int pbeg = c * PC;
    const int pend = min(pbeg + PC, NPTS);
#pragma unroll 2
    for (int pt = pbeg + (int)threadIdx.x * 4; pt < pend; pt += 1024 * 4) {
        int4   id = *(const int4*)(ridx + pt);
        float4 w  = *(const float4*)(pw + pt);
        float  r  = ratio[(pt >> 8) * 4 + b];
        unsigned r0 = (unsigned)(id.x - lo), r1 = (unsigned)(id.y - lo);
        unsigned r2 = (unsigned)(id.z - lo), r3 = (unsigned)(id.w - lo);
        if (r0 < VOXT) atomicAdd(&acc[r0], w.x * r);
        if (r1 < VOXT) atomicAdd(&acc[r1], w.y * r);
        if (r2 < VOXT) atomicAdd(&acc[r2], w.z * r);
        if (r3 < VOXT) atomicAdd(&acc[r3], w.w * r);
    }
    __syncthreads();
    float4* dst = (float4*)(part + ((size_t)c * 4 + b) * NVOX + lo);
    const float4* srcl = (const float4*)acc;
    for (int q = threadIdx.x; q < VOXT / 4; q += 1024) dst[q] = srcl[q];
}

__global__ __launch_bounds__(256) void k_conv1(
    const float* __restrict__ xt, const float* __restrict__ w1,
    const float* __restrict__ b1, float* __restrict__ h)
{
    int t = blockIdx.x * blockDim.x + threadIdx.x;
    int b = t >> 16;
    int v = t & 65535;
    int i = v >> 8, j = v & 255;
    float in[3][3];
#pragma unroll
    for (int di = 0; di < 3; ++di)
#pragma unroll
        for (int dj = 0; dj < 3; ++dj) {
            int ii = i + di - 1, jj = j + dj - 1;
            in[di][dj] = (ii >= 0 && ii < N0 && jj >= 0 && jj < N1)
                             ? xt[(size_t)((ii << 8) | jj) * 4 + b]
                             : 0.0f;
        }
    float* hp = h + (size_t)t * CH;
#pragma unroll
    for (int c = 0; c < CH; ++c) {
        float acc = b1[c];
#pragma unroll
        for (int di = 0; di < 3; ++di)
#pragma unroll
            for (int dj = 0; dj < 3; ++dj)
                acc += in[di][dj] * w1[c * 9 + di * 3 + dj];
        hp[c] = fmaxf(acc, 0.0f);
    }
}

__global__ __launch_bounds__(256) void k_combine(
    const float* __restrict__ h, const float* __restrict__ w2,
    const float* __restrict__ b2, const float* __restrict__ part,
    const float* __restrict__ xt_in, const float* __restrict__ osem,
    const float* __restrict__ adj, const float* __restrict__ nwp, int C,
    float* __restrict__ xt_out, float* __restrict__ out_planar)
{
    int t = blockIdx.x * blockDim.x + threadIdx.x;
    int b = t >> 16;
    int v = t & 65535;
    int i = v >> 8, j = v & 255;
    float o = b2[0];
#pragma unroll
    for (int di = 0; di < 3; ++di) {
        int ii = i + di - 1;
        if (ii < 0 || ii >= N0) continue;
#pragma unroll
        for (int dj = 0; dj < 3; ++dj) {
            int jj = j + dj - 1;
            if (jj < 0 || jj >= N1) continue;
            const float* hp = h + ((size_t)b * NVOX + ((ii << 8) | jj)) * CH;
#pragma unroll
            for (int c = 0; c < CH; ++c)
                o += hp[c] * w2[c * 9 + di * 3 + dj];
        }
    }
    float bk = 0.0f;
    for (int c = 0; c < C; ++c)
        bk += part[((size_t)c * 4 + b) * NVOX + v];
    float xv = xt_in[(size_t)v * 4 + b];
    float x_data = bk * xv / adj[(size_t)b * NSUB * NVOX + v];
    float xnew = osem[t] - x_data + nwp[0] * o;
    xnew = fmaxf(xnew, 0.0f);
    xt_out[(size_t)v * 4 + b] = xnew;
    if (out_planar) out_planar[t] = xnew;
}
// ------------------------------------------------------------------------------------

extern "C" void kernel_launch(void* const* d_in, const int* in_sizes, int n_in,
                              void* d_out, int out_size, void* d_ws, size_t ws_size,
                              hipStream_t stream) {
    const float* osem   = (const float*)d_in[0];
    const float* data   = (const float*)d_in[1];
    const float* mult   = (const float*)d_in[2];
    const float* contam = (const float*)d_in[3];
    const float* adj    = (const float*)d_in[4];
    const float* norm   = (const float*)d_in[5];
    const int*   ray_idx = (const int*)d_in[6];
    const float* pw     = (const float*)d_in[7];
    const float* w1     = (const float*)d_in[8];
    const float* b1     = (const float*)d_in[9];
    const float* w2     = (const float*)d_in[10];
    const float* b2     = (const float*)d_in[11];
    const float* nw     = (const float*)d_in[12];
    float* out = (float*)d_out;

    const size_t MB = 1024 * 1024;
    float* ws  = (float*)d_ws;
    float* xtA = ws;
    float* xtB = ws + (size_t)NVOX * 4;
    const int subsets[4] = {0, 2, 4, 6};

    // pk path: xtA(1M) xtB(1M) part(16.8M) packed(33.5M) back(1M) ratio(0.5M) = ~54MB
    bool use_pk = (ws_size >= 90 * MB);

    k_transpose<<<NVOX / 256, 256, 0, stream>>>(osem, xtA);

    if (use_pk) {
        const int PC = NPTS / CCH;  // 262144
        unsigned* part   = (unsigned*)(ws + (size_t)NVOX * 8);
        unsigned* packed = part + (size_t)CCH * 2 * NVOX;
        float*    backv  = (float*)(packed + (size_t)NPTS);
        float*    ratio  = backv + (size_t)NVOX * 4;

        float* xin = xtA;
        float* xout = xtB;
        for (int it = 0; it < 4; ++it) {
            int s = subsets[it];
            k_fwdpack<<<NLOR / 8, 256, 0, stream>>>(
                ray_idx + (size_t)s * NPTS, pw + (size_t)s * NPTS, xin,
                data + (size_t)s * NLOR, mult + (size_t)s * NLOR,
                contam + (size_t)s * NLOR, norm, ratio, packed);
            k_back_pk<<<dim3(CCH, 8), 1024, 0, stream>>>(packed, ratio, part, PC);
            k_reduce<<<dim3(NVOX / 512, 2), 256, 0, stream>>>(part, backv);
            k_net_combine<<<dim3(N0 / TI, N1 / TJ, BB), 256, 0, stream>>>(
                xin, w1, b1, w2, b2, backv, osem,
                adj + (size_t)s * NVOX, nw,
                xout, (it == 3) ? out : nullptr);
            float* tmp = xin; xin = xout; xout = tmp;
        }
    } else {
        int C = (ws_size >= (18 + 32) * MB + NVOX) ? 32
              : (ws_size >= (18 + 16) * MB + NVOX) ? 16 : 8;
        const int PC = NPTS / C;
        float* part = ws + (size_t)NVOX * 8;
        float* h    = part + (size_t)C * NVOX * 4;
        float* ratio = h;

        float* xin = xtA;
        float* xout = xtB;
        for (int it = 0; it < 4; ++it) {
            int s = subsets[it];
            const int*   rs = ray_idx + (size_t)s * NPTS;
            const float* ps = pw + (size_t)s * NPTS;
            k_fwd<<<NLOR / 4, 256, 0, stream>>>(
                rs, ps, xin,
                data + (size_t)s * NLOR, mult + (size_t)s * NLOR,
                contam + (size_t)s * NLOR, norm, ratio);
            k_back<<<dim3(C, 8), 1024, 0, stream>>>(rs, ps, ratio, part, PC);
            k_conv1<<<(BB * NVOX) / 256, 256, 0, stream>>>(xin, w1, b1, h);
            k_combine<<<(BB * NVOX) / 256, 256, 0, stream>>>(
                h, w2, b2, part, xin, osem,
                adj + (size_t)s * NVOX, nw, C,
                xout, (it == 3) ? out : nullptr);
            float* tmp = xin; xin = xout; xout = tmp;
        }
    }
}